// Round 14
// baseline (2227.911 us; speedup 1.0000x reference)
//
#include <hip/hip_runtime.h>
#include <hip/hip_bf16.h>
#include <math.h>

#define B_ 4
#define SEQ_ 2048
#define DIM_ 768
#define DEPTH_ 6
#define HEADS_ 12
#define DH_ 64
#define MF_ 256
#define FF_ 3072
#define ROWS_ 8192
#define BH_ 48
#define QKVW_ 2304
#define DN_ 0.3535533905932738f   /* 64^-0.25 */
#define RATIO_ 0.0625f            /* 256^-0.5 */
#define EPSK_ 1e-4f
#define EPSLN_ 1e-5f

typedef unsigned short u16;
typedef unsigned int   u32;
typedef __bf16 bf16x8 __attribute__((ext_vector_type(8)));
typedef u16    u16x8  __attribute__((ext_vector_type(8)));
typedef float  f32x4  __attribute__((ext_vector_type(4)));

__device__ inline u16 f2bf(float x){
  u32 u = __builtin_bit_cast(u32, x);
  return (u16)((u + 0x7FFFu + ((u>>16)&1u)) >> 16);
}
__device__ inline float bf2f(u16 v){ return __builtin_bit_cast(float, (u32)v<<16); }

__device__ inline void gload16(const u16* g, u16* lds){
  __builtin_amdgcn_global_load_lds(
    (const __attribute__((address_space(1))) u32*)(const void*)g,
    (__attribute__((address_space(3))) u32*)(void*)lds, 16, 0, 0);
}

// ---------------- embedding (h fp32) ----------------
__global__ void embed_kernel(const int* __restrict__ x, const float4* __restrict__ tok,
                             const float4* __restrict__ pos, float4* __restrict__ h){
  const int C4 = DIM_/4;
  long total = (long)ROWS_*C4;
  for (long i = (long)blockIdx.x*blockDim.x + threadIdx.x; i < total;
       i += (long)gridDim.x*blockDim.x){
    int row = (int)(i / C4); int c = (int)(i - (long)row*C4);
    int n = row & (SEQ_-1);
    float4 a = tok[(long)x[row]*C4 + c];
    float4 p = pos[(long)n*C4 + c];
    float4 o; o.x=a.x+p.x; o.y=a.y+p.y; o.z=a.z+p.z; o.w=a.w+p.w;
    h[i] = o;
  }
}

// ---------------- layernorm fp32 -> bf16 ----------------
__global__ __launch_bounds__(256) void ln_kernel(const float* __restrict__ X,
                          const float* __restrict__ g, const float* __restrict__ bta,
                          u16* __restrict__ Y){
  int row = blockIdx.x; int t = threadIdx.x;
  const float* xr = X + (long)row*DIM_;
  float v0 = xr[t], v1 = xr[t+256], v2 = xr[t+512];
  float s = v0+v1+v2;
  float ss = v0*v0+v1*v1+v2*v2;
  int lane = t&63, wid = t>>6;
  #pragma unroll
  for (int off=32; off; off>>=1){ s += __shfl_xor(s,off); ss += __shfl_xor(ss,off); }
  __shared__ float red[8];
  if (lane==0){ red[wid]=s; red[4+wid]=ss; }
  __syncthreads();
  s  = red[0]+red[1]+red[2]+red[3];
  ss = red[4]+red[5]+red[6]+red[7];
  float mu  = s*(1.0f/DIM_);
  float var = ss*(1.0f/DIM_) - mu*mu;
  float rs  = rsqrtf(var + EPSLN_);
  u16* yr = Y + (long)row*DIM_;
  yr[t]     = f2bf((v0-mu)*rs*g[t]     + bta[t]);
  yr[t+256] = f2bf((v1-mu)*rs*g[t+256] + bta[t+256]);
  yr[t+512] = f2bf((v2-mu)*rs*g[t+512] + bta[t+512]);
}

// 4x 768x768 transposes + proj hi/lo convert in one launch (z=0..3 weights, z=4 proj)
__global__ __launch_bounds__(256) void tconv5_kernel(const float* __restrict__ Wq,
        const float* __restrict__ Wk, const float* __restrict__ Wv,
        const float* __restrict__ Wo, const float* __restrict__ prj,
        u16* __restrict__ dst, u16* __restrict__ phi, u16* __restrict__ plo){
  int z = blockIdx.z;
  if (z == 4){
    int bid = blockIdx.y*24 + blockIdx.x;
    if (bid < 16){
      int i = bid*1024 + threadIdx.x*4;
      float4 v = *(const float4*)(prj + i);
      float vv[4] = {v.x, v.y, v.z, v.w};
      #pragma unroll
      for (int j=0;j<4;j++){
        u16 hh = f2bf(vv[j]);
        phi[i+j] = hh;
        plo[i+j] = f2bf(vv[j] - bf2f(hh));
      }
    }
    return;
  }
  __shared__ float tile[32][33];
  const float* W = (z==0)?Wq:(z==1)?Wk:(z==2)?Wv:Wo;
  u16* WT = dst + (long)z*589824;
  int n0 = blockIdx.x*32, k0 = blockIdx.y*32;
  int tx = threadIdx.x & 31, ty = threadIdx.x >> 5;
  #pragma unroll
  for (int i=0;i<32;i+=8) tile[ty+i][tx] = W[(long)(k0+ty+i)*768 + n0+tx];
  __syncthreads();
  #pragma unroll
  for (int i=0;i<32;i+=8) WT[(long)(n0+ty+i)*768 + k0+tx] = f2bf(tile[tx][ty+i]);
}

// w1 (768x3072) and w2 (3072x768) transposes in one launch (z picks)
__global__ __launch_bounds__(256) void tconvFF_kernel(const float* __restrict__ W1,
        const float* __restrict__ W2, u16* __restrict__ wt1, u16* __restrict__ wt2){
  __shared__ float tile[32][33];
  int z = blockIdx.z;
  const float* W; u16* WT; int K, N, n0, k0;
  if (z==0){ W=W1; WT=wt1; K=768;  N=3072; n0=blockIdx.x*32; k0=blockIdx.y*32; }
  else     { W=W2; WT=wt2; K=3072; N=768;  n0=blockIdx.y*32; k0=blockIdx.x*32; }
  int tx = threadIdx.x & 31, ty = threadIdx.x >> 5;
  #pragma unroll
  for (int i=0;i<32;i+=8) tile[ty+i][tx] = W[(long)(k0+ty+i)*N + n0+tx];
  __syncthreads();
  #pragma unroll
  for (int i=0;i<32;i+=8) WT[(long)(n0+ty+i)*K + k0+tx] = f2bf(tile[tx][ty+i]);
}

// ---------------- MFMA GEMM, BK=64 (two interleaved 32-k sub-buffers) ----------------
// CMODE: 0 = bf16 store (+bias,+gelu if ACT); 1 = fp32 C += (+bias)
template<int FM, int FN, int WM, int WN, int ACT, int CMODE, int BATCH>
__global__ __launch_bounds__(256) void mgemm(const u16* __restrict__ A,
     const u16* __restrict__ BT, const float* __restrict__ bias,
     void* __restrict__ Cv, const float* __restrict__ scale,
     int M, int N, int K, int ldC){
  (void)M; (void)scale;
  constexpr int BM = WM*FM*16, BN = WN*FN*16;
  constexpr int ACH = BM/16, BCH = BN/16;
  __shared__ u16 As[BM*64];
  __shared__ u16 Bs[BN*64];
  int tid = threadIdx.x; int w = tid>>6, l = tid&63;
  int bx, by;
  if (BATCH){ bx = blockIdx.x; by = blockIdx.y; }
  else {
    int bid = blockIdx.y*gridDim.x + blockIdx.x;
    int cpx = (gridDim.x*gridDim.y) >> 3;
    int swz = (bid & 7)*cpx + (bid >> 3);
    bx = swz % gridDim.x; by = swz / gridDim.x;
  }
  int m0 = by*BM, n0 = bx*BN;
  if (BATCH){
    int z = blockIdx.z;
    A  += (long)z*2048*K;
    BT += (long)z*(long)N*K;
  }
  f32x4 acc[FM][FN];
  #pragma unroll
  for (int i=0;i<FM;i++)
    #pragma unroll
    for (int j=0;j<FN;j++) acc[i][j] = (f32x4){0.f,0.f,0.f,0.f};

  const int row_l = l>>2, cq_l = l&3;
  const int wm = w / WN, wn = w % WN;
  const int kq = l>>4, rl15 = l&15;

  for (int k0=0; k0<K; k0+=64){
    __syncthreads();
    for (int c = w; c < 2*ACH; c += 4){
      int rc = c>>1, ks = c&1;
      int r = rc*16 + row_l;
      int gq = cq_l ^ ((r>>1)&3);
      gload16(A + (long)(m0+r)*K + k0 + ks*32 + gq*8, As + c*512);
    }
    for (int c = w; c < 2*BCH; c += 4){
      int rc = c>>1, ks = c&1;
      int r = rc*16 + row_l;
      int gq = cq_l ^ ((r>>1)&3);
      gload16(BT + (long)(n0+r)*K + k0 + ks*32 + gq*8, Bs + c*512);
    }
    __syncthreads();
    #pragma unroll
    for (int ks=0; ks<2; ks++){
      bf16x8 af[FM], bfr[FN];
      #pragma unroll
      for (int mi=0; mi<FM; mi++){
        int rr = (wm*FM + mi)*16 + rl15;
        int g = kq ^ ((rr>>1)&3);
        af[mi] = *(const bf16x8*)(As + ((rr>>4)*2 + ks)*512 + (rr&15)*32 + g*8);
      }
      #pragma unroll
      for (int ni=0; ni<FN; ni++){
        int rr = (wn*FN + ni)*16 + rl15;
        int g = kq ^ ((rr>>1)&3);
        bfr[ni] = *(const bf16x8*)(Bs + ((rr>>4)*2 + ks)*512 + (rr&15)*32 + g*8);
      }
      #pragma unroll
      for (int mi=0; mi<FM; mi++)
        #pragma unroll
        for (int ni=0; ni<FN; ni++)
          acc[mi][ni] = __builtin_amdgcn_mfma_f32_16x16x32_bf16(af[mi], bfr[ni], acc[mi][ni], 0, 0, 0);
    }
  }

  int cc = l&15, rq = l>>4;
  #pragma unroll
  for (int mi=0; mi<FM; mi++){
    #pragma unroll
    for (int ni=0; ni<FN; ni++){
      int gcol = n0 + (wn*FN+ni)*16 + cc;
      float bv = bias ? bias[gcol] : 0.f;
      #pragma unroll
      for (int r4=0; r4<4; r4++){
        int grow = m0 + (wm*FM+mi)*16 + rq*4 + r4;
        float v = acc[mi][ni][r4] + bv;
        if (ACT) v = 0.5f*v*(1.0f + erff(v*0.70710678118654752f));
        if (CMODE==1){
          float* C = (float*)Cv;
          C[(long)grow*ldC + gcol] += v;
        } else {
          ((u16*)Cv)[(long)grow*ldC + gcol] = f2bf(v);
        }
      }
    }
  }
}

// ---- FAVOR K feature GEMM (batched per z): xd = K_head[2048x64] @ projbf[256x64]^T
// MODE 0: per-block max of xd*DN -> fmaxbuf; MODE 1: in-block st, in-block diag,
// kp = bf16(RATIO*(exp(xd*DN - diag - st) + EPS)); ksum partials -> ksp
template<int MODE>
__global__ __launch_bounds__(256) void featgemm(const u16* __restrict__ X,
     const u16* __restrict__ PB, u16* __restrict__ kp,
     float* __restrict__ fmaxbuf, float* __restrict__ ksp){
  __shared__ u16 As[128*32];
  __shared__ u16 Bs[128*32];
  __shared__ float wred[4];
  __shared__ float diag_s[128];
  int tid = threadIdx.x; int w = tid>>6, l = tid&63;
  int n0 = blockIdx.x*128, m0 = blockIdx.y*128;
  int z = blockIdx.z;
  const u16* A = X + (long)(z/HEADS_)*SEQ_*QKVW_ + (z%HEADS_)*DH_;
  float st = 0.f;
  if (MODE==1){
    float mm = (l<32) ? fmaxbuf[z*32 + l] : -1e30f;
    #pragma unroll
    for (int off=32; off; off>>=1) mm = fmaxf(mm, __shfl_xor(mm,off));
    st = mm;
  }
  f32x4 acc[4][4];
  #pragma unroll
  for (int i=0;i<4;i++)
    #pragma unroll
    for (int j=0;j<4;j++) acc[i][j] = (f32x4){0.f,0.f,0.f,0.f};
  float rdiag = 0.f;
  const int row_l = l>>2, cq_l = l&3;
  const int wm = w>>1, wn = w&1;
  const int kq = l>>4, rl15 = l&15;

  for (int k0=0; k0<64; k0+=32){
    __syncthreads();
    for (int c = w; c < 8; c += 4){
      int r = c*16 + row_l;
      int gq = cq_l ^ ((r>>1)&3);
      gload16(A + (long)(m0+r)*QKVW_ + k0 + gq*8, As + c*512);
    }
    for (int c = w; c < 8; c += 4){
      int r = c*16 + row_l;
      int gq = cq_l ^ ((r>>1)&3);
      gload16(PB + (long)(n0+r)*64 + k0 + gq*8, Bs + c*512);
    }
    __syncthreads();
    if (MODE==1){
      int dr = tid>>1, dc = tid&1;
      const u16* rb = As + (dr>>4)*512 + (dr&15)*32 + dc*16;
      u16x8 a0 = *(const u16x8*)rb;
      u16x8 a1 = *(const u16x8*)(rb + 8);
      float s = 0.f;
      #pragma unroll
      for (int j=0;j<8;j++){
        float f0 = bf2f(a0[j]), f1 = bf2f(a1[j]);
        s += f0*f0 + f1*f1;
      }
      s += __shfl_xor(s,1);
      rdiag += s;
    }
    bf16x8 af[4], bfr[4];
    #pragma unroll
    for (int mi=0; mi<4; mi++){
      int rr = (wm*4 + mi)*16 + rl15;
      int g = kq ^ ((rr>>1)&3);
      af[mi] = *(const bf16x8*)(As + rr*32 + g*8);
    }
    #pragma unroll
    for (int ni=0; ni<4; ni++){
      int rr = (wn*4 + ni)*16 + rl15;
      int g = kq ^ ((rr>>1)&3);
      bfr[ni] = *(const bf16x8*)(Bs + rr*32 + g*8);
    }
    #pragma unroll
    for (int mi=0; mi<4; mi++)
      #pragma unroll
      for (int ni=0; ni<4; ni++)
        acc[mi][ni] = __builtin_amdgcn_mfma_f32_16x16x32_bf16(af[mi], bfr[ni], acc[mi][ni], 0, 0, 0);
  }

  if (MODE==0){
    float bm = -1e30f;
    #pragma unroll
    for (int mi=0;mi<4;mi++)
      #pragma unroll
      for (int ni=0;ni<4;ni++)
        #pragma unroll
        for (int r4=0;r4<4;r4++) bm = fmaxf(bm, acc[mi][ni][r4]);
    bm *= DN_;
    #pragma unroll
    for (int off=32; off; off>>=1) bm = fmaxf(bm, __shfl_xor(bm,off));
    if (l==0) wred[w] = bm;
    __syncthreads();
    if (tid==0)
      fmaxbuf[z*32 + blockIdx.y*2 + blockIdx.x] =
        fmaxf(fmaxf(wred[0],wred[1]),fmaxf(wred[2],wred[3]));
  } else {
    if ((tid&1)==0) diag_s[tid>>1] = 0.5f*DN_*DN_*rdiag;
    __syncthreads();
    __shared__ float ksred[128][8];
    int cc = l&15, rq = l>>4;
    #pragma unroll
    for (int ni=0; ni<4; ni++){
      int gcol = n0 + (wn*4+ni)*16 + cc;
      float cs = 0.f;
      #pragma unroll
      for (int mi=0; mi<4; mi++){
        #pragma unroll
        for (int r4=0; r4<4; r4++){
          int lrow = (wm*4+mi)*16 + rq*4 + r4;
          float v = acc[mi][ni][r4]*DN_;
          float e = RATIO_*(expf(v - diag_s[lrow] - st) + EPSK_);
          u16 eb = f2bf(e);
          kp[((long)z*SEQ_ + m0 + lrow)*MF_ + gcol] = eb;
          cs += bf2f(eb);
        }
      }
      ksred[(wn*4+ni)*16 + cc][wm*4 + rq] = cs;
    }
    __syncthreads();
    if (tid < 128){
      float s = 0.f;
      #pragma unroll
      for (int q=0;q<8;q++) s += ksred[tid][q];
      ksp[((long)z*16 + blockIdx.y)*MF_ + n0 + tid] = s;
    }
  }
}

// ---- Q feature GEMM + diag + ksum-reduce + rowmax + FUSED PV ----
// Phase 1: feature GEMM (hi/lo proj) -> acc; Phase 2: qp -> LDS + dinv -> LDS;
// Phase 3: out[64n x 64d] = (qp_lds @ ctxT[z]) * dinv, stored to attn.
// grid (32, BH_). ctxT B-frags read directly from global (L2-resident, 32KB/z).
__global__ __launch_bounds__(256) void qfeatpv(const u16* __restrict__ X,
     const u16* __restrict__ PH, const u16* __restrict__ PL,
     const float* __restrict__ ksp, const u16* __restrict__ ctxT,
     u16* __restrict__ attn){
  __shared__ u16 As[64*32];       // 4 KB
  __shared__ u16 uB[16896];       // phase1: Bh=uB[0..8191], Bl=uB[8192..16383] (32KB)
                                  // phase3: qp_lds[64][264] (33792 B)
  __shared__ float ksl[256];
  __shared__ float dqs[64];
  __shared__ float rmax[64][4];
  __shared__ float rsum[64][4];
  __shared__ float dinvs[64];
  u16* Bh = uB;
  u16* Bl = uB + 8192;
  int tid = threadIdx.x; int w = tid>>6, l = tid&63;
  int n0 = blockIdx.x*64;
  int z = blockIdx.y;
  int b = z/HEADS_, hh = z%HEADS_;
  const u16* A = X + (long)b*SEQ_*QKVW_ + hh*DH_;  // Q cols
  {
    float s = 0.f;
    #pragma unroll
    for (int c=0;c<16;c++) s += ksp[((long)z*16+c)*MF_ + tid];
    ksl[tid] = s;
  }
  f32x4 acc[4][4];
  #pragma unroll
  for (int i=0;i<4;i++)
    #pragma unroll
    for (int j=0;j<4;j++) acc[i][j] = (f32x4){0.f,0.f,0.f,0.f};
  float rdiag = 0.f;
  const int row_l = l>>2, cq_l = l&3;
  const int kq = l>>4, rl15 = l&15;

  for (int k0=0; k0<64; k0+=32){
    __syncthreads();
    {
      int r = w*16 + row_l;
      int gq = cq_l ^ ((r>>1)&3);
      gload16(A + (long)(n0+r)*QKVW_ + k0 + gq*8, As + w*512);
    }
    for (int c = w; c < 16; c += 4){
      int r = c*16 + row_l;
      int gq = cq_l ^ ((r>>1)&3);
      gload16(PH + (long)r*64 + k0 + gq*8, Bh + c*512);
      gload16(PL + (long)r*64 + k0 + gq*8, Bl + c*512);
    }
    __syncthreads();
    { // per-row sumsq from staged LDS
      int dr = tid>>2, dq4 = tid&3;
      const u16* rb = As + (dr>>4)*512 + (dr&15)*32 + dq4*8;
      u16x8 a0 = *(const u16x8*)rb;
      float s = 0.f;
      #pragma unroll
      for (int j=0;j<8;j++){ float f = bf2f(a0[j]); s += f*f; }
      s += __shfl_xor(s,1); s += __shfl_xor(s,2);
      rdiag += s;
    }
    bf16x8 af[4], bh[4], bl[4];
    #pragma unroll
    for (int mi=0; mi<4; mi++){
      int rr = mi*16 + rl15;
      int g = kq ^ ((rr>>1)&3);
      af[mi] = *(const bf16x8*)(As + rr*32 + g*8);
    }
    #pragma unroll
    for (int ni=0; ni<4; ni++){
      int rr = (w*4 + ni)*16 + rl15;
      int g = kq ^ ((rr>>1)&3);
      bh[ni] = *(const bf16x8*)(Bh + rr*32 + g*8);
      bl[ni] = *(const bf16x8*)(Bl + rr*32 + g*8);
    }
    #pragma unroll
    for (int mi=0; mi<4; mi++)
      #pragma unroll
      for (int ni=0; ni<4; ni++){
        acc[mi][ni] = __builtin_amdgcn_mfma_f32_16x16x32_bf16(af[mi], bh[ni], acc[mi][ni], 0, 0, 0);
        acc[mi][ni] = __builtin_amdgcn_mfma_f32_16x16x32_bf16(af[mi], bl[ni], acc[mi][ni], 0, 0, 0);
      }
  }

  if ((tid&3)==0) dqs[tid>>2] = 0.5f*DN_*DN_*rdiag;
  __syncthreads();          // also guarantees all Bh/Bl MFMA reads are done

  int cc = l&15, rq = l>>4;
  // per-row max over all 256 m
  #pragma unroll
  for (int mi=0; mi<4; mi++){
    #pragma unroll
    for (int r4=0; r4<4; r4++){
      float pm = fmaxf(fmaxf(acc[mi][0][r4],acc[mi][1][r4]),
                       fmaxf(acc[mi][2][r4],acc[mi][3][r4]));
      pm = fmaxf(pm, __shfl_xor(pm,1)); pm = fmaxf(pm, __shfl_xor(pm,2));
      pm = fmaxf(pm, __shfl_xor(pm,4)); pm = fmaxf(pm, __shfl_xor(pm,8));
      if (cc==0) rmax[mi*16 + rq*4 + r4][w] = pm;
    }
  }
  __syncthreads();
  // phase 2: qp -> uB (as qp_lds[row][264]), dv partials
  #pragma unroll
  for (int mi=0; mi<4; mi++){
    #pragma unroll
    for (int r4=0; r4<4; r4++){
      int row = mi*16 + rq*4 + r4;
      float mx = fmaxf(fmaxf(rmax[row][0],rmax[row][1]),
                       fmaxf(rmax[row][2],rmax[row][3])) * DN_;
      float dq = dqs[row];
      float dv = 0.f;
      #pragma unroll
      for (int ni=0; ni<4; ni++){
        int col = w*64 + ni*16 + cc;
        float qpv = RATIO_*(expf(acc[mi][ni][r4]*DN_ - dq - mx) + EPSK_);
        u16 qb = f2bf(qpv);
        uB[row*264 + col] = qb;
        dv += bf2f(qb)*ksl[col];
      }
      dv += __shfl_xor(dv,1); dv += __shfl_xor(dv,2);
      dv += __shfl_xor(dv,4); dv += __shfl_xor(dv,8);
      if (cc==0) rsum[row][w] = dv;
    }
  }
  __syncthreads();
  if (tid < 64){
    float s = rsum[tid][0]+rsum[tid][1]+rsum[tid][2]+rsum[tid][3];
    dinvs[tid] = 1.0f/s;
  }
  __syncthreads();

  // phase 3: PV — out[64n][64d] = qp_lds @ ctxT[z]^T(d-major), *dinv
  const u16* cz = ctxT + (long)z*(64*MF_);
  f32x4 acc2[4];
  #pragma unroll
  for (int ni=0;ni<4;ni++) acc2[ni] = (f32x4){0.f,0.f,0.f,0.f};
  #pragma unroll
  for (int ks2=0; ks2<8; ks2++){
    bf16x8 aq = *(const bf16x8*)(&uB[(w*16+rl15)*264 + ks2*32 + kq*8]);
    #pragma unroll
    for (int ni=0;ni<4;ni++){
      bf16x8 bv = *(const bf16x8*)(cz + (ni*16+rl15)*MF_ + ks2*32 + kq*8);
      acc2[ni] = __builtin_amdgcn_mfma_f32_16x16x32_bf16(aq, bv, acc2[ni], 0, 0, 0);
    }
  }
  long cb = ((long)b*SEQ_ + n0)*DIM_ + hh*DH_;
  #pragma unroll
  for (int ni=0;ni<4;ni++){
    #pragma unroll
    for (int r4=0;r4<4;r4++){
      int row = w*16 + rq*4 + r4;
      float v = acc2[ni][r4] * dinvs[row];
      attn[cb + (long)row*DIM_ + ni*16 + cc] = f2bf(v);
    }
  }
}

// ---- ctxgemm: ctxT-partial[d=64][m=256] = sum_n V[n][d]*kp[n][m] (TN, transpose-on-stage)
__global__ __launch_bounds__(256) void ctxgemm(const u16* __restrict__ qkv,
     const u16* __restrict__ kp, float* __restrict__ part){
  int kc = blockIdx.x;      // 0..1 (1024 rows each)
  int z  = blockIdx.y;
  int b = z/HEADS_, hh = z%HEADS_;
  int tid = threadIdx.x; int w = tid>>6, l = tid&63;
  __shared__ u16 Vt[64*40];
  __shared__ u16 Kpt[256*40];
  f32x4 acc[4][4];
  #pragma unroll
  for (int i=0;i<4;i++)
    #pragma unroll
    for (int j=0;j<4;j++) acc[i][j] = (f32x4){0.f,0.f,0.f,0.f};
  int n_l = tid&31, grp = tid>>5;
  const int kq = l>>4, rl15 = l&15;
  const long vbase = (long)b*SEQ_*QKVW_ + hh*DH_ + 1536;
  const long kbase = (long)z*SEQ_*MF_;

  for (int s=0; s<32; s++){
    int nG = kc*1024 + s*32 + n_l;
    __syncthreads();
    {
      u16x8 v = *(const u16x8*)(qkv + vbase + (long)nG*QKVW_ + grp*8);
      #pragma unroll
      for (int j=0;j<8;j++) Vt[(grp*8+j)*40 + n_l] = v[j];
    }
    {
      const u16* src = kp + kbase + (long)nG*MF_ + grp*32;
      #pragma unroll
      for (int q=0;q<4;q++){
        u16x8 v = *(const u16x8*)(src + q*8);
        #pragma unroll
        for (int j=0;j<8;j++) Kpt[(grp*32+q*8+j)*40 + n_l] = v[j];
      }
    }
    __syncthreads();
    bf16x8 af[4], bfr[4];
    #pragma unroll
    for (int mi=0; mi<4; mi++)
      af[mi] = *(const bf16x8*)(Vt + (mi*16+rl15)*40 + kq*8);
    #pragma unroll
    for (int ni=0; ni<4; ni++)
      bfr[ni] = *(const bf16x8*)(Kpt + ((w*4+ni)*16+rl15)*40 + kq*8);
    #pragma unroll
    for (int mi=0; mi<4; mi++)
      #pragma unroll
      for (int ni=0; ni<4; ni++)
        acc[mi][ni] = __builtin_amdgcn_mfma_f32_16x16x32_bf16(af[mi], bfr[ni], acc[mi][ni], 0, 0, 0);
  }

  int cc = l&15, rq = l>>4;
  float* pb = part + ((long)kc*BH_ + z)*(64*MF_);
  #pragma unroll
  for (int mi=0; mi<4; mi++){
    #pragma unroll
    for (int ni=0; ni<4; ni++){
      int m = (w*4+ni)*16 + cc;
      #pragma unroll
      for (int r4=0; r4<4; r4++){
        int d = mi*16 + rq*4 + r4;
        pb[(long)d*MF_ + m] = acc[mi][ni][r4];
      }
    }
  }
}

// reduce 2 ctx partials -> ctxT bf16 [z][d][m]
__global__ void ctx_reduce2(const float* __restrict__ part, u16* __restrict__ ctxT){
  const long NT = (long)BH_*64*MF_; // 786432
  for (long i = (long)blockIdx.x*256 + threadIdx.x; i < NT; i += (long)gridDim.x*256){
    ctxT[i] = f2bf(part[i] + part[NT + i]);
  }
}

// ---------------- pooler: LN(row0) fused + matvec + tanh ----------------
__global__ __launch_bounds__(256) void poolmv_kernel(const float* __restrict__ h,
        const float* __restrict__ g, const float* __restrict__ bta,
        const float* __restrict__ Wp, const float* __restrict__ bp,
        float* __restrict__ pooled){
  int c = blockIdx.x;      // 12 chunks of 64 cols
  int b = blockIdx.y;
  __shared__ float xs[768];
  __shared__ float red8[8];
  __shared__ float red[64][5];
  int t = threadIdx.x;
  const float* row = h + (long)b*SEQ_*DIM_;
  float v0=row[t], v1=row[t+256], v2=row[t+512];
  float s = v0+v1+v2, ss = v0*v0+v1*v1+v2*v2;
  int lane=t&63, wid=t>>6;
  #pragma unroll
  for (int off=32; off; off>>=1){ s += __shfl_xor(s,off); ss += __shfl_xor(ss,off); }
  if (lane==0){ red8[wid]=s; red8[4+wid]=ss; }
  __syncthreads();
  s  = red8[0]+red8[1]+red8[2]+red8[3];
  ss = red8[4]+red8[5]+red8[6]+red8[7];
  float mu = s*(1.0f/DIM_);
  float var = ss*(1.0f/DIM_) - mu*mu;
  float rs = rsqrtf(var + EPSLN_);
  xs[t]     = (v0-mu)*rs*g[t]     + bta[t];
  xs[t+256] = (v1-mu)*rs*g[t+256] + bta[t+256];
  xs[t+512] = (v2-mu)*rs*g[t+512] + bta[t+512];
  __syncthreads();
  int col_l = t & 63, seg = t >> 6;
  int col = c*64 + col_l;
  const float* wp = Wp + col;
  float a = 0.f;
  #pragma unroll 4
  for (int i = seg*192; i < (seg+1)*192; i++) a += xs[i]*wp[(long)i*DIM_];
  red[col_l][seg] = a;
  __syncthreads();
  if (t < 64){
    float sv = red[t][0]+red[t][1]+red[t][2]+red[t][3] + bp[c*64+t];
    pooled[b*DIM_ + c*64 + t] = tanhf(sv);
  }
}

// ---------------- classifier: out[b][c] = pooled[b]·Wc[:,c] + bc ----------------
__global__ __launch_bounds__(256) void cls_kernel(const float* __restrict__ pooled,
        const float* __restrict__ Wc, const float* __restrict__ bc,
        float* __restrict__ out){
  int t = threadIdx.x;
  int b = t >> 6, lane = t & 63;
  float a0 = 0.f, a1 = 0.f;
  for (int i = lane; i < 768; i += 64){
    float p = pooled[b*DIM_ + i];
    a0 += p*Wc[i*2]; a1 += p*Wc[i*2+1];
  }
  #pragma unroll
  for (int off=32; off; off>>=1){ a0 += __shfl_xor(a0,off); a1 += __shfl_xor(a1,off); }
  if (lane==0){ out[b*2] = a0 + bc[0]; out[b*2+1] = a1 + bc[1]; }
}

extern "C" void kernel_launch(void* const* d_in, const int* in_sizes, int n_in,
                              void* d_out, int out_size, void* d_ws, size_t ws_size,
                              hipStream_t stream) {
  (void)in_sizes; (void)n_in; (void)out_size; (void)ws_size;
  const int*   x    = (const int*)  d_in[0];
  const float* tok  = (const float*)d_in[1];
  const float* pos  = (const float*)d_in[2];
  const float* ln1g = (const float*)d_in[3];
  const float* ln1b = (const float*)d_in[4];
  const float* Wq   = (const float*)d_in[5];
  const float* Wk   = (const float*)d_in[6];
  const float* Wv   = (const float*)d_in[7];
  const float* Wo   = (const float*)d_in[8];
  const float* bo   = (const float*)d_in[9];
  const float* proj = (const float*)d_in[10];
  const float* ln2g = (const float*)d_in[11];
  const float* ln2b = (const float*)d_in[12];
  const float* W1   = (const float*)d_in[13];
  const float* b1   = (const float*)d_in[14];
  const float* W2   = (const float*)d_in[15];
  const float* b2   = (const float*)d_in[16];
  const float* lnfg = (const float*)d_in[17];
  const float* lnfb = (const float*)d_in[18];
  const float* Wp   = (const float*)d_in[19];
  const float* bp   = (const float*)d_in[20];
  const float* Wc   = (const float*)d_in[21];
  const float* bc   = (const float*)d_in[22];
  float* out = (float*)d_out;

  // ---- workspace layout (bytes), peak 142,016,512 (<= proven 142,024,960) ----
  char* wsb = (char*)d_ws;
  float* h     = (float*)(wsb + 0);                 // 25165824 B fp32
  u16*   ybf   = (u16*)  (wsb + 25165824);          // 12582912 B region (ln out)
  // aliases inside ybf region (written only AFTER QKV gemm consumed ln1-out):
  float* ctxp2 = (float*)(wsb + 25165824);          // 6291456 B (2 partials)
  float* ksp   = (float*)(wsb + 32243712);          // 786432 B (16 partials)
  float* fmaxp = (float*)(wsb + 33030144);          // 6144 B
  // post-loop pooler alias:
  float* pooled= (float*)(wsb + 25178112);          // 12288 B
  u16*   qkv   = (u16*)  (wsb + 37748736);          // 37748736 B = [8192][2304] bf16
  u16*   ffnbf = (u16*)  (wsb + 75497472);          // 50331648 B region
  u16*   kp    = (u16*)  (wsb + 75497472);          // kp; attn overwrites after ctxgemm
  u16*   attnbf= (u16*)  (wsb + 75497472);          // [8192][768] bf16 (12.58 MB)
  u16*   wT    = (u16*)  (wsb + 125829120);         // 14155776 B
  u16*   ctxT  = (u16*)  (wsb + 139984896);         // 1572864 B
  u16*   projbf= (u16*)  (wsb + 141950976);         // 32768 B (hi) — outside ybf region
  u16*   projlo= (u16*)  (wsb + 141983744);         // 32768 B (lo) -> 142016512

  u16* wtq = wT;                 // [2304][768] stacked q,k,v (+o right after)
  u16* wto = wT + 1769472;
  u16* wt1 = wT + 2359296;       // [3072][768]
  u16* wt2 = wT + 4718592;       // [768][3072]

  embed_kernel<<<2048,256,0,stream>>>(x,(const float4*)tok,(const float4*)pos,(float4*)h);

  dim3 gD64(6, 128);            // N=768, 64-row tiles (FFN2 / Wo)
  dim3 gQKV(18, 64);            // N=2304
  dim3 gF(24, 64);              // N=3072
  dim3 gFG(2, 16, BH_);         // featgemm K
  dim3 gQF(32, BH_);            // qfeatpv

  for (int l=0; l<DEPTH_; l++){
    const float* wq  = Wq + (size_t)l*DIM_*DIM_;
    const float* wk  = Wk + (size_t)l*DIM_*DIM_;
    const float* wv  = Wv + (size_t)l*DIM_*DIM_;
    const float* wo  = Wo + (size_t)l*DIM_*DIM_;
    const float* prj = proj + (size_t)l*MF_*DH_;
    const float* w1  = W1 + (size_t)l*DIM_*FF_;
    const float* w2  = W2 + (size_t)l*FF_*DIM_;

    tconv5_kernel<<<dim3(24,24,5),256,0,stream>>>(wq, wk, wv, wo, prj, wtq, projbf, projlo);
    tconvFF_kernel<<<dim3(96,24,2),256,0,stream>>>(w1, w2, wt1, wt2);

    ln_kernel<<<ROWS_,256,0,stream>>>(h, ln1g+(size_t)l*DIM_, ln1b+(size_t)l*DIM_, ybf);
    mgemm<4,4,2,2,0,0,0><<<gQKV,256,0,stream>>>(ybf, wtq, nullptr, qkv, nullptr, ROWS_, QKVW_, 768, QKVW_);

    // ---- K-side FAVOR on MFMA ----
    featgemm<0><<<gFG,256,0,stream>>>(qkv + 768, projbf, nullptr, fmaxp, nullptr);
    featgemm<1><<<gFG,256,0,stream>>>(qkv + 768, projbf, kp, fmaxp, ksp);
    ctxgemm<<<dim3(2,BH_),256,0,stream>>>(qkv, kp, ctxp2);
    ctx_reduce2<<<768,256,0,stream>>>(ctxp2, ctxT);

    // ---- Q-side + fused PV (attnbf overwrites kp AFTER ctxgemm consumed it) ----
    qfeatpv<<<gQF,256,0,stream>>>(qkv, projbf, projlo, ksp, ctxT, attnbf);

    mgemm<2,4,2,2,0,1,0><<<gD64,256,0,stream>>>(attnbf, wto, bo+(size_t)l*DIM_, h, nullptr, ROWS_, 768, 768, 768);

    ln_kernel<<<ROWS_,256,0,stream>>>(h, ln2g+(size_t)l*DIM_, ln2b+(size_t)l*DIM_, ybf);
    mgemm<4,4,2,2,1,0,0><<<gF,256,0,stream>>>(ybf, wt1, b1+(size_t)l*FF_, ffnbf, nullptr, ROWS_, 3072, 768, 3072);
    mgemm<2,4,2,2,0,1,0><<<gD64,256,0,stream>>>(ffnbf, wt2, b2+(size_t)l*DIM_, h, nullptr, ROWS_, 768, 3072, 768);
  }

  poolmv_kernel<<<dim3(12,B_),256,0,stream>>>(h, lnfg, lnfb, Wp, bp, pooled);
  cls_kernel<<<1,256,0,stream>>>(pooled, Wc, bc, out);
}

// Round 15
// 2186.136 us; speedup vs baseline: 1.0191x; 1.0191x over previous
//
#include <hip/hip_runtime.h>
#include <hip/hip_bf16.h>
#include <math.h>

#define B_ 4
#define SEQ_ 2048
#define DIM_ 768
#define DEPTH_ 6
#define HEADS_ 12
#define DH_ 64
#define MF_ 256
#define FF_ 3072
#define ROWS_ 8192
#define BH_ 48
#define QKVW_ 2304
#define DN_ 0.3535533905932738f   /* 64^-0.25 */
#define RATIO_ 0.0625f            /* 256^-0.5 */
#define EPSK_ 1e-4f
#define EPSLN_ 1e-5f

typedef unsigned short u16;
typedef unsigned int   u32;
typedef __bf16 bf16x8 __attribute__((ext_vector_type(8)));
typedef u16    u16x8  __attribute__((ext_vector_type(8)));
typedef float  f32x4  __attribute__((ext_vector_type(4)));

__device__ inline u16 f2bf(float x){
  u32 u = __builtin_bit_cast(u32, x);
  return (u16)((u + 0x7FFFu + ((u>>16)&1u)) >> 16);
}
__device__ inline float bf2f(u16 v){ return __builtin_bit_cast(float, (u32)v<<16); }

__device__ inline void gload16(const u16* g, u16* lds){
  __builtin_amdgcn_global_load_lds(
    (const __attribute__((address_space(1))) u32*)(const void*)g,
    (__attribute__((address_space(3))) u32*)(void*)lds, 16, 0, 0);
}

// ---------------- embedding (h fp32) ----------------
__global__ void embed_kernel(const int* __restrict__ x, const float4* __restrict__ tok,
                             const float4* __restrict__ pos, float4* __restrict__ h){
  const int C4 = DIM_/4;
  long total = (long)ROWS_*C4;
  for (long i = (long)blockIdx.x*blockDim.x + threadIdx.x; i < total;
       i += (long)gridDim.x*blockDim.x){
    int row = (int)(i / C4); int c = (int)(i - (long)row*C4);
    int n = row & (SEQ_-1);
    float4 a = tok[(long)x[row]*C4 + c];
    float4 p = pos[(long)n*C4 + c];
    float4 o; o.x=a.x+p.x; o.y=a.y+p.y; o.z=a.z+p.z; o.w=a.w+p.w;
    h[i] = o;
  }
}

// ---------------- layernorm fp32 -> bf16 ----------------
__global__ __launch_bounds__(256) void ln_kernel(const float* __restrict__ X,
                          const float* __restrict__ g, const float* __restrict__ bta,
                          u16* __restrict__ Y){
  int row = blockIdx.x; int t = threadIdx.x;
  const float* xr = X + (long)row*DIM_;
  float v0 = xr[t], v1 = xr[t+256], v2 = xr[t+512];
  float s = v0+v1+v2;
  float ss = v0*v0+v1*v1+v2*v2;
  int lane = t&63, wid = t>>6;
  #pragma unroll
  for (int off=32; off; off>>=1){ s += __shfl_xor(s,off); ss += __shfl_xor(ss,off); }
  __shared__ float red[8];
  if (lane==0){ red[wid]=s; red[4+wid]=ss; }
  __syncthreads();
  s  = red[0]+red[1]+red[2]+red[3];
  ss = red[4]+red[5]+red[6]+red[7];
  float mu  = s*(1.0f/DIM_);
  float var = ss*(1.0f/DIM_) - mu*mu;
  float rs  = rsqrtf(var + EPSLN_);
  u16* yr = Y + (long)row*DIM_;
  yr[t]     = f2bf((v0-mu)*rs*g[t]     + bta[t]);
  yr[t+256] = f2bf((v1-mu)*rs*g[t+256] + bta[t+256]);
  yr[t+512] = f2bf((v2-mu)*rs*g[t+512] + bta[t+512]);
}

// 4x 768x768 transposes + proj hi/lo convert in one launch (z=0..3 weights, z=4 proj)
__global__ __launch_bounds__(256) void tconv5_kernel(const float* __restrict__ Wq,
        const float* __restrict__ Wk, const float* __restrict__ Wv,
        const float* __restrict__ Wo, const float* __restrict__ prj,
        u16* __restrict__ dst, u16* __restrict__ phi, u16* __restrict__ plo){
  int z = blockIdx.z;
  if (z == 4){
    int bid = blockIdx.y*24 + blockIdx.x;
    if (bid < 16){
      int i = bid*1024 + threadIdx.x*4;
      float4 v = *(const float4*)(prj + i);
      float vv[4] = {v.x, v.y, v.z, v.w};
      #pragma unroll
      for (int j=0;j<4;j++){
        u16 hh = f2bf(vv[j]);
        phi[i+j] = hh;
        plo[i+j] = f2bf(vv[j] - bf2f(hh));
      }
    }
    return;
  }
  __shared__ float tile[32][33];
  const float* W = (z==0)?Wq:(z==1)?Wk:(z==2)?Wv:Wo;
  u16* WT = dst + (long)z*589824;
  int n0 = blockIdx.x*32, k0 = blockIdx.y*32;
  int tx = threadIdx.x & 31, ty = threadIdx.x >> 5;
  #pragma unroll
  for (int i=0;i<32;i+=8) tile[ty+i][tx] = W[(long)(k0+ty+i)*768 + n0+tx];
  __syncthreads();
  #pragma unroll
  for (int i=0;i<32;i+=8) WT[(long)(n0+ty+i)*768 + k0+tx] = f2bf(tile[tx][ty+i]);
}

// w1 (768x3072) and w2 (3072x768) transposes in one launch (z picks)
__global__ __launch_bounds__(256) void tconvFF_kernel(const float* __restrict__ W1,
        const float* __restrict__ W2, u16* __restrict__ wt1, u16* __restrict__ wt2){
  __shared__ float tile[32][33];
  int z = blockIdx.z;
  const float* W; u16* WT; int K, N, n0, k0;
  if (z==0){ W=W1; WT=wt1; K=768;  N=3072; n0=blockIdx.x*32; k0=blockIdx.y*32; }
  else     { W=W2; WT=wt2; K=3072; N=768;  n0=blockIdx.y*32; k0=blockIdx.x*32; }
  int tx = threadIdx.x & 31, ty = threadIdx.x >> 5;
  #pragma unroll
  for (int i=0;i<32;i+=8) tile[ty+i][tx] = W[(long)(k0+ty+i)*N + n0+tx];
  __syncthreads();
  #pragma unroll
  for (int i=0;i<32;i+=8) WT[(long)(n0+ty+i)*K + k0+tx] = f2bf(tile[tx][ty+i]);
}

// ---------------- MFMA GEMM, BK=64 (two interleaved 32-k sub-buffers) ----------------
// C = f(A[M,K]bf16 @ BT[N,K]^T bf16 + bias)
// CMODE: 0 = bf16 store (+bias,+gelu if ACT); 1 = fp32 C += (+bias); 2 = bf16 store * scale[row]
// BATCH==0: XCD-aware bijective block swizzle (requires gridDim.x*gridDim.y % 8 == 0)
template<int FM, int FN, int WM, int WN, int ACT, int CMODE, int BATCH>
__global__ __launch_bounds__(256) void mgemm(const u16* __restrict__ A,
     const u16* __restrict__ BT, const float* __restrict__ bias,
     void* __restrict__ Cv, const float* __restrict__ scale,
     int M, int N, int K, int ldC){
  (void)M;
  constexpr int BM = WM*FM*16, BN = WN*FN*16;
  constexpr int ACH = BM/16, BCH = BN/16;
  __shared__ u16 As[BM*64];
  __shared__ u16 Bs[BN*64];
  int tid = threadIdx.x; int w = tid>>6, l = tid&63;
  int bx, by;
  if (BATCH){ bx = blockIdx.x; by = blockIdx.y; }
  else {
    int bid = blockIdx.y*gridDim.x + blockIdx.x;
    int cpx = (gridDim.x*gridDim.y) >> 3;
    int swz = (bid & 7)*cpx + (bid >> 3);
    bx = swz % gridDim.x; by = swz / gridDim.x;
  }
  int m0 = by*BM, n0 = bx*BN;
  long coff = 0, srow0 = 0;
  if (BATCH){
    int z = blockIdx.z;
    A  += (long)z*2048*K;
    BT += (long)z*(long)N*K;
    coff  = (long)(z/HEADS_)*SEQ_*(long)ldC + (long)(z%HEADS_)*64;
    srow0 = (long)z*SEQ_;
  }
  f32x4 acc[FM][FN];
  #pragma unroll
  for (int i=0;i<FM;i++)
    #pragma unroll
    for (int j=0;j<FN;j++) acc[i][j] = (f32x4){0.f,0.f,0.f,0.f};

  const int row_l = l>>2, cq_l = l&3;
  const int wm = w / WN, wn = w % WN;
  const int kq = l>>4, rl15 = l&15;

  for (int k0=0; k0<K; k0+=64){
    __syncthreads();
    for (int c = w; c < 2*ACH; c += 4){
      int rc = c>>1, ks = c&1;
      int r = rc*16 + row_l;
      int gq = cq_l ^ ((r>>1)&3);
      gload16(A + (long)(m0+r)*K + k0 + ks*32 + gq*8, As + c*512);
    }
    for (int c = w; c < 2*BCH; c += 4){
      int rc = c>>1, ks = c&1;
      int r = rc*16 + row_l;
      int gq = cq_l ^ ((r>>1)&3);
      gload16(BT + (long)(n0+r)*K + k0 + ks*32 + gq*8, Bs + c*512);
    }
    __syncthreads();
    #pragma unroll
    for (int ks=0; ks<2; ks++){
      bf16x8 af[FM], bfr[FN];
      #pragma unroll
      for (int mi=0; mi<FM; mi++){
        int rr = (wm*FM + mi)*16 + rl15;
        int g = kq ^ ((rr>>1)&3);
        af[mi] = *(const bf16x8*)(As + ((rr>>4)*2 + ks)*512 + (rr&15)*32 + g*8);
      }
      #pragma unroll
      for (int ni=0; ni<FN; ni++){
        int rr = (wn*FN + ni)*16 + rl15;
        int g = kq ^ ((rr>>1)&3);
        bfr[ni] = *(const bf16x8*)(Bs + ((rr>>4)*2 + ks)*512 + (rr&15)*32 + g*8);
      }
      #pragma unroll
      for (int mi=0; mi<FM; mi++)
        #pragma unroll
        for (int ni=0; ni<FN; ni++)
          acc[mi][ni] = __builtin_amdgcn_mfma_f32_16x16x32_bf16(af[mi], bfr[ni], acc[mi][ni], 0, 0, 0);
    }
  }

  int cc = l&15, rq = l>>4;
  #pragma unroll
  for (int mi=0; mi<FM; mi++){
    #pragma unroll
    for (int ni=0; ni<FN; ni++){
      int gcol = n0 + (wn*FN+ni)*16 + cc;
      float bv = bias ? bias[gcol] : 0.f;
      #pragma unroll
      for (int r4=0; r4<4; r4++){
        int grow = m0 + (wm*FM+mi)*16 + rq*4 + r4;
        float v = acc[mi][ni][r4] + bv;
        if (ACT) v = 0.5f*v*(1.0f + erff(v*0.70710678118654752f));
        if (CMODE==1){
          float* C = (float*)Cv;
          C[(long)grow*ldC + gcol] += v;
        } else if (CMODE==2){
          v *= scale[srow0 + grow];
          ((u16*)Cv)[coff + (long)grow*ldC + gcol] = f2bf(v);
        } else {
          ((u16*)Cv)[(long)grow*ldC + gcol] = f2bf(v);
        }
      }
    }
  }
}

// ---- FAVOR K feature GEMM (batched per z): xd = K_head[2048x64] @ projbf[256x64]^T
// MODE 0: per-block max of xd*DN -> fmaxbuf; MODE 1: in-block st, in-block diag,
// kp = bf16(RATIO*(exp(xd*DN - diag - st) + EPS)); ksum partials -> ksp
template<int MODE>
__global__ __launch_bounds__(256) void featgemm(const u16* __restrict__ X,
     const u16* __restrict__ PB, u16* __restrict__ kp,
     float* __restrict__ fmaxbuf, float* __restrict__ ksp){
  __shared__ u16 As[128*32];
  __shared__ u16 Bs[128*32];
  __shared__ float wred[4];
  __shared__ float diag_s[128];
  int tid = threadIdx.x; int w = tid>>6, l = tid&63;
  int n0 = blockIdx.x*128, m0 = blockIdx.y*128;
  int z = blockIdx.z;
  const u16* A = X + (long)(z/HEADS_)*SEQ_*QKVW_ + (z%HEADS_)*DH_;
  float st = 0.f;
  if (MODE==1){
    float mm = (l<32) ? fmaxbuf[z*32 + l] : -1e30f;
    #pragma unroll
    for (int off=32; off; off>>=1) mm = fmaxf(mm, __shfl_xor(mm,off));
    st = mm;
  }
  f32x4 acc[4][4];
  #pragma unroll
  for (int i=0;i<4;i++)
    #pragma unroll
    for (int j=0;j<4;j++) acc[i][j] = (f32x4){0.f,0.f,0.f,0.f};
  float rdiag = 0.f;
  const int row_l = l>>2, cq_l = l&3;
  const int wm = w>>1, wn = w&1;
  const int kq = l>>4, rl15 = l&15;

  for (int k0=0; k0<64; k0+=32){
    __syncthreads();
    for (int c = w; c < 8; c += 4){
      int r = c*16 + row_l;
      int gq = cq_l ^ ((r>>1)&3);
      gload16(A + (long)(m0+r)*QKVW_ + k0 + gq*8, As + c*512);
    }
    for (int c = w; c < 8; c += 4){
      int r = c*16 + row_l;
      int gq = cq_l ^ ((r>>1)&3);
      gload16(PB + (long)(n0+r)*64 + k0 + gq*8, Bs + c*512);
    }
    __syncthreads();
    if (MODE==1){
      int dr = tid>>1, dc = tid&1;
      const u16* rb = As + (dr>>4)*512 + (dr&15)*32 + dc*16;
      u16x8 a0 = *(const u16x8*)rb;
      u16x8 a1 = *(const u16x8*)(rb + 8);
      float s = 0.f;
      #pragma unroll
      for (int j=0;j<8;j++){
        float f0 = bf2f(a0[j]), f1 = bf2f(a1[j]);
        s += f0*f0 + f1*f1;
      }
      s += __shfl_xor(s,1);
      rdiag += s;
    }
    bf16x8 af[4], bfr[4];
    #pragma unroll
    for (int mi=0; mi<4; mi++){
      int rr = (wm*4 + mi)*16 + rl15;
      int g = kq ^ ((rr>>1)&3);
      af[mi] = *(const bf16x8*)(As + rr*32 + g*8);
    }
    #pragma unroll
    for (int ni=0; ni<4; ni++){
      int rr = (wn*4 + ni)*16 + rl15;
      int g = kq ^ ((rr>>1)&3);
      bfr[ni] = *(const bf16x8*)(Bs + rr*32 + g*8);
    }
    #pragma unroll
    for (int mi=0; mi<4; mi++)
      #pragma unroll
      for (int ni=0; ni<4; ni++)
        acc[mi][ni] = __builtin_amdgcn_mfma_f32_16x16x32_bf16(af[mi], bfr[ni], acc[mi][ni], 0, 0, 0);
  }

  if (MODE==0){
    float bm = -1e30f;
    #pragma unroll
    for (int mi=0;mi<4;mi++)
      #pragma unroll
      for (int ni=0;ni<4;ni++)
        #pragma unroll
        for (int r4=0;r4<4;r4++) bm = fmaxf(bm, acc[mi][ni][r4]);
    bm *= DN_;
    #pragma unroll
    for (int off=32; off; off>>=1) bm = fmaxf(bm, __shfl_xor(bm,off));
    if (l==0) wred[w] = bm;
    __syncthreads();
    if (tid==0)
      fmaxbuf[z*32 + blockIdx.y*2 + blockIdx.x] =
        fmaxf(fmaxf(wred[0],wred[1]),fmaxf(wred[2],wred[3]));
  } else {
    if ((tid&1)==0) diag_s[tid>>1] = 0.5f*DN_*DN_*rdiag;
    __syncthreads();
    __shared__ float ksred[128][8];
    int cc = l&15, rq = l>>4;
    #pragma unroll
    for (int ni=0; ni<4; ni++){
      int gcol = n0 + (wn*4+ni)*16 + cc;
      float cs = 0.f;
      #pragma unroll
      for (int mi=0; mi<4; mi++){
        #pragma unroll
        for (int r4=0; r4<4; r4++){
          int lrow = (wm*4+mi)*16 + rq*4 + r4;
          float v = acc[mi][ni][r4]*DN_;
          float e = RATIO_*(expf(v - diag_s[lrow] - st) + EPSK_);
          u16 eb = f2bf(e);
          kp[((long)z*SEQ_ + m0 + lrow)*MF_ + gcol] = eb;
          cs += bf2f(eb);
        }
      }
      ksred[(wn*4+ni)*16 + cc][wm*4 + rq] = cs;
    }
    __syncthreads();
    if (tid < 128){
      float s = 0.f;
      #pragma unroll
      for (int q=0;q<8;q++) s += ksred[tid][q];
      ksp[((long)z*16 + blockIdx.y)*MF_ + n0 + tid] = s;
    }
  }
}

// ---- Q feature GEMM + in-block diag + ksum-reduce + per-row max + qp + dinv ----
// hi/lo split proj for near-fp32 argument precision. grid (32, BH_)
__global__ __launch_bounds__(256) void qfeatgemm(const u16* __restrict__ X,
     const u16* __restrict__ PH, const u16* __restrict__ PL,
     const float* __restrict__ ksp, u16* __restrict__ qp, float* __restrict__ dinv){
  __shared__ u16 As[64*32];       // 4 KB
  __shared__ u16 Bh[256*32];      // 16 KB
  __shared__ u16 Bl[256*32];      // 16 KB
  __shared__ float ksl[256];
  __shared__ float dqs[64];
  __shared__ float rmax[64][4];
  __shared__ float rsum[64][4];
  int tid = threadIdx.x; int w = tid>>6, l = tid&63;
  int n0 = blockIdx.x*64;
  int z = blockIdx.y;
  const u16* A = X + (long)(z/HEADS_)*SEQ_*QKVW_ + (z%HEADS_)*DH_;  // Q cols
  {
    float s = 0.f;
    #pragma unroll
    for (int c=0;c<16;c++) s += ksp[((long)z*16+c)*MF_ + tid];
    ksl[tid] = s;
  }
  f32x4 acc[4][4];
  #pragma unroll
  for (int i=0;i<4;i++)
    #pragma unroll
    for (int j=0;j<4;j++) acc[i][j] = (f32x4){0.f,0.f,0.f,0.f};
  float rdiag = 0.f;
  const int row_l = l>>2, cq_l = l&3;
  const int kq = l>>4, rl15 = l&15;

  for (int k0=0; k0<64; k0+=32){
    __syncthreads();
    { // A: 4 chunks of 16 rows, one per wave
      int r = w*16 + row_l;
      int gq = cq_l ^ ((r>>1)&3);
      gload16(A + (long)(n0+r)*QKVW_ + k0 + gq*8, As + w*512);
    }
    for (int c = w; c < 16; c += 4){
      int r = c*16 + row_l;
      int gq = cq_l ^ ((r>>1)&3);
      gload16(PH + (long)r*64 + k0 + gq*8, Bh + c*512);
      gload16(PL + (long)r*64 + k0 + gq*8, Bl + c*512);
    }
    __syncthreads();
    { // per-row sumsq from staged LDS
      int dr = tid>>2, dq4 = tid&3;
      const u16* rb = As + (dr>>4)*512 + (dr&15)*32 + dq4*8;
      u16x8 a0 = *(const u16x8*)rb;
      float s = 0.f;
      #pragma unroll
      for (int j=0;j<8;j++){ float f = bf2f(a0[j]); s += f*f; }
      s += __shfl_xor(s,1); s += __shfl_xor(s,2);
      rdiag += s;
    }
    bf16x8 af[4], bh[4], bl[4];
    #pragma unroll
    for (int mi=0; mi<4; mi++){
      int rr = mi*16 + rl15;
      int g = kq ^ ((rr>>1)&3);
      af[mi] = *(const bf16x8*)(As + rr*32 + g*8);
    }
    #pragma unroll
    for (int ni=0; ni<4; ni++){
      int rr = (w*4 + ni)*16 + rl15;
      int g = kq ^ ((rr>>1)&3);
      bh[ni] = *(const bf16x8*)(Bh + rr*32 + g*8);
      bl[ni] = *(const bf16x8*)(Bl + rr*32 + g*8);
    }
    #pragma unroll
    for (int mi=0; mi<4; mi++)
      #pragma unroll
      for (int ni=0; ni<4; ni++){
        acc[mi][ni] = __builtin_amdgcn_mfma_f32_16x16x32_bf16(af[mi], bh[ni], acc[mi][ni], 0, 0, 0);
        acc[mi][ni] = __builtin_amdgcn_mfma_f32_16x16x32_bf16(af[mi], bl[ni], acc[mi][ni], 0, 0, 0);
      }
  }

  if ((tid&3)==0) dqs[tid>>2] = 0.5f*DN_*DN_*rdiag;
  __syncthreads();

  int cc = l&15, rq = l>>4;
  // per-row max over all 256 m
  #pragma unroll
  for (int mi=0; mi<4; mi++){
    #pragma unroll
    for (int r4=0; r4<4; r4++){
      float pm = fmaxf(fmaxf(acc[mi][0][r4],acc[mi][1][r4]),
                       fmaxf(acc[mi][2][r4],acc[mi][3][r4]));
      pm = fmaxf(pm, __shfl_xor(pm,1)); pm = fmaxf(pm, __shfl_xor(pm,2));
      pm = fmaxf(pm, __shfl_xor(pm,4)); pm = fmaxf(pm, __shfl_xor(pm,8));
      if (cc==0) rmax[mi*16 + rq*4 + r4][w] = pm;
    }
  }
  __syncthreads();
  #pragma unroll
  for (int mi=0; mi<4; mi++){
    #pragma unroll
    for (int r4=0; r4<4; r4++){
      int row = mi*16 + rq*4 + r4;
      float mx = fmaxf(fmaxf(rmax[row][0],rmax[row][1]),
                       fmaxf(rmax[row][2],rmax[row][3])) * DN_;
      float dq = dqs[row];
      float dv = 0.f;
      #pragma unroll
      for (int ni=0; ni<4; ni++){
        int col = w*64 + ni*16 + cc;
        float qpv = RATIO_*(expf(acc[mi][ni][r4]*DN_ - dq - mx) + EPSK_);
        u16 qb = f2bf(qpv);
        qp[((long)z*SEQ_ + n0 + row)*MF_ + col] = qb;
        dv += bf2f(qb)*ksl[col];
      }
      dv += __shfl_xor(dv,1); dv += __shfl_xor(dv,2);
      dv += __shfl_xor(dv,4); dv += __shfl_xor(dv,8);
      if (cc==0) rsum[row][w] = dv;
    }
  }
  __syncthreads();
  if (tid < 64){
    float s = rsum[tid][0]+rsum[tid][1]+rsum[tid][2]+rsum[tid][3];
    dinv[(long)z*SEQ_ + n0 + tid] = 1.0f/s;
  }
}

// ---- ctxgemm: ctxT-partial[d=64][m=256] = sum_n V[n][d]*kp[n][m] (TN, transpose-on-stage)
// grid (2 n-chunks, BH_) = 96 blocks; DOUBLE-BUFFERED (statically-named buffer pairs so
// the compiler can overlap next-tile global loads + ds_writes under current-tile MFMAs;
// latency-bound regime at <1 block/CU — ILP is the only hiding mechanism here).
__global__ __launch_bounds__(256) void ctxgemm(const u16* __restrict__ qkv,
     const u16* __restrict__ kp, float* __restrict__ part){
  int kc = blockIdx.x;      // 0..1 (1024 rows each)
  int z  = blockIdx.y;
  int b = z/HEADS_, hh = z%HEADS_;
  int tid = threadIdx.x; int w = tid>>6, l = tid&63;
  __shared__ u16 Vt0[64*40],  Vt1[64*40];
  __shared__ u16 Kpt0[256*40], Kpt1[256*40];
  f32x4 acc[4][4];
  #pragma unroll
  for (int i=0;i<4;i++)
    #pragma unroll
    for (int j=0;j<4;j++) acc[i][j] = (f32x4){0.f,0.f,0.f,0.f};
  int n_l = tid&31, grp = tid>>5;
  const int kq = l>>4, rl15 = l&15;
  const long vbase = (long)b*SEQ_*QKVW_ + hh*DH_ + 1536;
  const long kbase = (long)z*SEQ_*MF_;

#define CTX_STAGE(VT, KPT, S) do { \
    int nG_ = kc*1024 + (S)*32 + n_l; \
    u16x8 v_ = *(const u16x8*)(qkv + vbase + (long)nG_*QKVW_ + grp*8); \
    _Pragma("unroll") \
    for (int j_=0;j_<8;j_++) VT[(grp*8+j_)*40 + n_l] = v_[j_]; \
    const u16* src_ = kp + kbase + (long)nG_*MF_ + grp*32; \
    _Pragma("unroll") \
    for (int q_=0;q_<4;q_++){ \
      u16x8 vv_ = *(const u16x8*)(src_ + q_*8); \
      _Pragma("unroll") \
      for (int j_=0;j_<8;j_++) KPT[(grp*32+q_*8+j_)*40 + n_l] = vv_[j_]; \
    } } while(0)

#define CTX_COMPUTE(VT, KPT) do { \
    bf16x8 af_[4], bf_[4]; \
    _Pragma("unroll") \
    for (int mi_=0; mi_<4; mi_++) \
      af_[mi_] = *(const bf16x8*)(VT + (mi_*16+rl15)*40 + kq*8); \
    _Pragma("unroll") \
    for (int ni_=0; ni_<4; ni_++) \
      bf_[ni_] = *(const bf16x8*)(KPT + ((w*4+ni_)*16+rl15)*40 + kq*8); \
    _Pragma("unroll") \
    for (int mi_=0; mi_<4; mi_++) \
      _Pragma("unroll") \
      for (int ni_=0; ni_<4; ni_++) \
        acc[mi_][ni_] = __builtin_amdgcn_mfma_f32_16x16x32_bf16(af_[mi_], bf_[ni_], acc[mi_][ni_], 0, 0, 0); \
  } while(0)

  CTX_STAGE(Vt0, Kpt0, 0);
  __syncthreads();
  #pragma unroll 1
  for (int s=0; s<32; s+=2){
    CTX_STAGE(Vt1, Kpt1, s+1);   // prefetch odd tile while computing even
    CTX_COMPUTE(Vt0, Kpt0);
    __syncthreads();
    if (s+2 < 32) CTX_STAGE(Vt0, Kpt0, s+2);
    CTX_COMPUTE(Vt1, Kpt1);
    __syncthreads();
  }
#undef CTX_STAGE
#undef CTX_COMPUTE

  int cc = l&15, rq = l>>4;
  float* pb = part + ((long)kc*BH_ + z)*(64*MF_);
  #pragma unroll
  for (int mi=0; mi<4; mi++){
    #pragma unroll
    for (int ni=0; ni<4; ni++){
      int m = (w*4+ni)*16 + cc;
      #pragma unroll
      for (int r4=0; r4<4; r4++){
        int d = mi*16 + rq*4 + r4;
        pb[(long)d*MF_ + m] = acc[mi][ni][r4];
      }
    }
  }
}

// reduce 2 ctx partials -> ctxT bf16 [z][d][m]
__global__ void ctx_reduce2(const float* __restrict__ part, u16* __restrict__ ctxT){
  const long NT = (long)BH_*64*MF_; // 786432
  for (long i = (long)blockIdx.x*256 + threadIdx.x; i < NT; i += (long)gridDim.x*256){
    ctxT[i] = f2bf(part[i] + part[NT + i]);
  }
}

// ---------------- pooler: LN(row0) fused + matvec + tanh ----------------
__global__ __launch_bounds__(256) void poolmv_kernel(const float* __restrict__ h,
        const float* __restrict__ g, const float* __restrict__ bta,
        const float* __restrict__ Wp, const float* __restrict__ bp,
        float* __restrict__ pooled){
  int c = blockIdx.x;      // 12 chunks of 64 cols
  int b = blockIdx.y;
  __shared__ float xs[768];
  __shared__ float red8[8];
  __shared__ float red[64][5];
  int t = threadIdx.x;
  const float* row = h + (long)b*SEQ_*DIM_;
  float v0=row[t], v1=row[t+256], v2=row[t+512];
  float s = v0+v1+v2, ss = v0*v0+v1*v1+v2*v2;
  int lane=t&63, wid=t>>6;
  #pragma unroll
  for (int off=32; off; off>>=1){ s += __shfl_xor(s,off); ss += __shfl_xor(ss,off); }
  if (lane==0){ red8[wid]=s; red8[4+wid]=ss; }
  __syncthreads();
  s  = red8[0]+red8[1]+red8[2]+red8[3];
  ss = red8[4]+red8[5]+red8[6]+red8[7];
  float mu = s*(1.0f/DIM_);
  float var = ss*(1.0f/DIM_) - mu*mu;
  float rs = rsqrtf(var + EPSLN_);
  xs[t]     = (v0-mu)*rs*g[t]     + bta[t];
  xs[t+256] = (v1-mu)*rs*g[t+256] + bta[t+256];
  xs[t+512] = (v2-mu)*rs*g[t+512] + bta[t+512];
  __syncthreads();
  int col_l = t & 63, seg = t >> 6;
  int col = c*64 + col_l;
  const float* wp = Wp + col;
  float a = 0.f;
  #pragma unroll 4
  for (int i = seg*192; i < (seg+1)*192; i++) a += xs[i]*wp[(long)i*DIM_];
  red[col_l][seg] = a;
  __syncthreads();
  if (t < 64){
    float sv = red[t][0]+red[t][1]+red[t][2]+red[t][3] + bp[c*64+t];
    pooled[b*DIM_ + c*64 + t] = tanhf(sv);
  }
}

// ---------------- classifier: out[b][c] = pooled[b]·Wc[:,c] + bc ----------------
__global__ __launch_bounds__(256) void cls_kernel(const float* __restrict__ pooled,
        const float* __restrict__ Wc, const float* __restrict__ bc,
        float* __restrict__ out){
  int t = threadIdx.x;
  int b = t >> 6, lane = t & 63;
  float a0 = 0.f, a1 = 0.f;
  for (int i = lane; i < 768; i += 64){
    float p = pooled[b*DIM_ + i];
    a0 += p*Wc[i*2]; a1 += p*Wc[i*2+1];
  }
  #pragma unroll
  for (int off=32; off; off>>=1){ a0 += __shfl_xor(a0,off); a1 += __shfl_xor(a1,off); }
  if (lane==0){ out[b*2] = a0 + bc[0]; out[b*2+1] = a1 + bc[1]; }
}

extern "C" void kernel_launch(void* const* d_in, const int* in_sizes, int n_in,
                              void* d_out, int out_size, void* d_ws, size_t ws_size,
                              hipStream_t stream) {
  (void)in_sizes; (void)n_in; (void)out_size; (void)ws_size;
  const int*   x    = (const int*)  d_in[0];
  const float* tok  = (const float*)d_in[1];
  const float* pos  = (const float*)d_in[2];
  const float* ln1g = (const float*)d_in[3];
  const float* ln1b = (const float*)d_in[4];
  const float* Wq   = (const float*)d_in[5];
  const float* Wk   = (const float*)d_in[6];
  const float* Wv   = (const float*)d_in[7];
  const float* Wo   = (const float*)d_in[8];
  const float* bo   = (const float*)d_in[9];
  const float* proj = (const float*)d_in[10];
  const float* ln2g = (const float*)d_in[11];
  const float* ln2b = (const float*)d_in[12];
  const float* W1   = (const float*)d_in[13];
  const float* b1   = (const float*)d_in[14];
  const float* W2   = (const float*)d_in[15];
  const float* b2   = (const float*)d_in[16];
  const float* lnfg = (const float*)d_in[17];
  const float* lnfb = (const float*)d_in[18];
  const float* Wp   = (const float*)d_in[19];
  const float* bp   = (const float*)d_in[20];
  const float* Wc   = (const float*)d_in[21];
  const float* bc   = (const float*)d_in[22];
  float* out = (float*)d_out;

  // ---- workspace layout (bytes), peak 142,016,512 (<= proven 142,024,960) ----
  char* wsb = (char*)d_ws;
  float* h     = (float*)(wsb + 0);                 // 25165824 B fp32
  u16*   ybf   = (u16*)  (wsb + 25165824);          // 12582912 B region (ln out / attn out)
  // aliases inside ybf region (written only AFTER QKV gemm consumed ln1-out):
  float* ctxp2 = (float*)(wsb + 25165824);          // 6291456 B (2 partials) -> 31457280
  float* ksp   = (float*)(wsb + 32243712);          // 786432 B (16 partials)
  float* fmaxp = (float*)(wsb + 33030144);          // 6144 B
  // post-loop pooler alias (ybf region dead then):
  float* pooled= (float*)(wsb + 25178112);          // 12288 B
  u16*   qkv   = (u16*)  (wsb + 37748736);          // 37748736 B = [8192][2304] bf16
  u16*   ffnbf = (u16*)  (wsb + 75497472);          // 50331648 B region
  u16*   kp    = (u16*)  (wsb + 75497472);          // alias: kp then qp then ffn
  u16*   qp    = (u16*)  (wsb + 75497472);
  u16*   wT    = (u16*)  (wsb + 125829120);         // 14155776 B
  u16*   ctxT  = (u16*)  (wsb + 139984896);         // 1572864 B
  float* dinv  = (float*)(wsb + 141557760);         // 393216 B -> 141950976
  u16*   projbf= (u16*)  (wsb + 141950976);         // 32768 B (hi)  — OUTSIDE ybf region
  u16*   projlo= (u16*)  (wsb + 141983744);         // 32768 B (lo) -> 142016512
  u16* attnbf  = ybf;

  u16* wtq = wT;                 // [2304][768] stacked q,k,v (+o right after)
  u16* wto = wT + 1769472;
  u16* wt1 = wT + 2359296;       // [3072][768]
  u16* wt2 = wT + 4718592;       // [768][3072]

  embed_kernel<<<2048,256,0,stream>>>(x,(const float4*)tok,(const float4*)pos,(float4*)h);

  dim3 gD64(6, 128);            // N=768, 64-row tiles (FFN2 / Wo)
  dim3 gQKV(18, 64);            // N=2304
  dim3 gF(24, 64);              // N=3072
  dim3 gQ2(1, 16, BH_);         // PV batched
  dim3 gFG(2, 16, BH_);         // featgemm K
  dim3 gQF(32, BH_);            // qfeatgemm

  for (int l=0; l<DEPTH_; l++){
    const float* wq  = Wq + (size_t)l*DIM_*DIM_;
    const float* wk  = Wk + (size_t)l*DIM_*DIM_;
    const float* wv  = Wv + (size_t)l*DIM_*DIM_;
    const float* wo  = Wo + (size_t)l*DIM_*DIM_;
    const float* prj = proj + (size_t)l*MF_*DH_;
    const float* w1  = W1 + (size_t)l*DIM_*FF_;
    const float* w2  = W2 + (size_t)l*FF_*DIM_;

    tconv5_kernel<<<dim3(24,24,5),256,0,stream>>>(wq, wk, wv, wo, prj, wtq, projbf, projlo);
    tconvFF_kernel<<<dim3(96,24,2),256,0,stream>>>(w1, w2, wt1, wt2);

    ln_kernel<<<ROWS_,256,0,stream>>>(h, ln1g+(size_t)l*DIM_, ln1b+(size_t)l*DIM_, ybf);
    mgemm<4,4,2,2,0,0,0><<<gQKV,256,0,stream>>>(ybf, wtq, nullptr, qkv, nullptr, ROWS_, QKVW_, 768, QKVW_);

    // ---- K-side FAVOR on MFMA ----
    featgemm<0><<<gFG,256,0,stream>>>(qkv + 768, projbf, nullptr, fmaxp, nullptr);
    featgemm<1><<<gFG,256,0,stream>>>(qkv + 768, projbf, kp, fmaxp, ksp);
    ctxgemm<<<dim3(2,BH_),256,0,stream>>>(qkv, kp, ctxp2);
    ctx_reduce2<<<768,256,0,stream>>>(ctxp2, ctxT);

    // ---- Q-side on MFMA + PV (qp overwrites kp AFTER ctxgemm consumed it) ----
    qfeatgemm<<<gQF,256,0,stream>>>(qkv, projbf, projlo, ksp, qp, dinv);
    mgemm<2,4,4,1,0,2,1><<<gQ2,256,0,stream>>>(qp, ctxT, nullptr, attnbf, dinv, SEQ_, 64, 256, 768);

    mgemm<2,4,2,2,0,1,0><<<gD64,256,0,stream>>>(attnbf, wto, bo+(size_t)l*DIM_, h, nullptr, ROWS_, 768, 768, 768);

    ln_kernel<<<ROWS_,256,0,stream>>>(h, ln2g+(size_t)l*DIM_, ln2b+(size_t)l*DIM_, ybf);
    mgemm<4,4,2,2,1,0,0><<<gF,256,0,stream>>>(ybf, wt1, b1+(size_t)l*FF_, ffnbf, nullptr, ROWS_, 3072, 768, 3072);
    mgemm<2,4,2,2,0,1,0><<<gD64,256,0,stream>>>(ffnbf, wt2, b2+(size_t)l*DIM_, h, nullptr, ROWS_, 768, 3072, 768);
  }

  poolmv_kernel<<<dim3(12,B_),256,0,stream>>>(h, lnfg, lnfb, Wp, bp, pooled);
  cls_kernel<<<1,256,0,stream>>>(pooled, Wc, bc, out);
}